// Round 9
// baseline (89327.777 us; speedup 1.0000x reference)
//
#include <hip/hip_runtime.h>

typedef short bf16x8 __attribute__((ext_vector_type(8)));
typedef float f32x4 __attribute__((ext_vector_type(4)));

#define DEV __device__ __forceinline__

constexpr int SEQ = 2048;
constexpr int HID = 4096;
constexpr int NH  = 32;
constexpr int NKV = 8;
constexpr int DH  = 128;
constexpr int FF  = 14336;
constexpr int QKVN = NH * DH + 2 * NKV * DH;  // 6144

DEV unsigned short f2bf(float f) {
  union { float f; unsigned u; } x; x.f = f;
  unsigned r = x.u + 0x7fffu + ((x.u >> 16) & 1u);
  return (unsigned short)(r >> 16);
}
DEV float bf2f(unsigned short u) {
  union { unsigned u; float f; } x; x.u = ((unsigned)u) << 16; return x.f;
}
DEV void gload16(const void* g, void* l) {
  __builtin_amdgcn_global_load_lds(
      (const __attribute__((address_space(1))) unsigned*)g,
      (__attribute__((address_space(3))) unsigned*)l, 16, 0, 0);
}

// ---------------------------------------------------------------- RMSNorm
__global__ __launch_bounds__(256) void rmsnorm_kernel(
    const float* __restrict__ x, const float* __restrict__ w,
    unsigned short* __restrict__ out) {
  const int row = blockIdx.x;
  const int tid = threadIdx.x;
  const float* xr = x + (size_t)row * HID;
  float4 v[4];
  float ss = 0.f;
#pragma unroll
  for (int i = 0; i < 4; ++i) {
    v[i] = *(const float4*)(xr + i * 1024 + tid * 4);
    ss += v[i].x * v[i].x + v[i].y * v[i].y + v[i].z * v[i].z + v[i].w * v[i].w;
  }
#pragma unroll
  for (int m = 1; m < 64; m <<= 1) ss += __shfl_xor(ss, m);
  __shared__ float red[4];
  if ((tid & 63) == 0) red[tid >> 6] = ss;
  __syncthreads();
  float tot = red[0] + red[1] + red[2] + red[3];
  float rms = rsqrtf(tot / (float)HID + 1e-5f);
  unsigned short* orow = out + (size_t)row * HID;
#pragma unroll
  for (int i = 0; i < 4; ++i) {
    int base = i * 1024 + tid * 4;
    ushort4 o;
    o.x = f2bf(v[i].x * rms * w[base + 0]);
    o.y = f2bf(v[i].y * rms * w[base + 1]);
    o.z = f2bf(v[i].z * rms * w[base + 2]);
    o.w = f2bf(v[i].w * rms * w[base + 3]);
    *(ushort4*)(orow + base) = o;
  }
}

// ---------------------------------------------------------------- RoPE (in-place, strided)
__global__ __launch_bounds__(256) void rope_kernel(unsigned short* __restrict__ x,
                                                   int nheads, int ld) {
  const int gid = blockIdx.x * 256 + threadIdx.x;
  const int i = gid & 63;
  const int t = gid >> 6;
  const int s = t / nheads;
  const int hh = t - s * nheads;
  float ang = (float)s * exp2f((float)i * (-29.897352853986263f / 64.f));
  float sn, cs;
  sincosf(ang, &sn, &cs);
  size_t base = (size_t)s * ld + hh * DH + i;
  float x1 = bf2f(x[base]);
  float x2 = bf2f(x[base + 64]);
  x[base]      = f2bf(x1 * cs - x2 * sn);
  x[base + 64] = f2bf(x2 * cs + x1 * sn);
}

// ---------------------------------------------------------------- combine (final)
__global__ __launch_bounds__(256) void combine_kernel(
    const float* __restrict__ p0, const float* __restrict__ p1,
    const float* __restrict__ res, float* __restrict__ out) {
  const size_t i = ((size_t)blockIdx.x * 256 + threadIdx.x) * 4;
  float4 a = *(const float4*)(p0 + i);
  float4 b = *(const float4*)(p1 + i);
  float4 c = *(const float4*)(res + i);
  float4 o;
  o.x = a.x + b.x + c.x;
  o.y = a.y + b.y + c.y;
  o.z = a.z + b.z + c.z;
  o.w = a.w + b.w + c.w;
  *(float4*)(out + i) = o;
}

// ---------------------------------------------------------------- combine + rmsnorm
__global__ __launch_bounds__(256) void combine_rms_kernel(
    const float* __restrict__ p0, const float* __restrict__ p1,
    const float* __restrict__ res, const float* __restrict__ w,
    float* __restrict__ h2, unsigned short* __restrict__ xn2) {
  const int row = blockIdx.x;
  const int tid = threadIdx.x;
  const size_t base = (size_t)row * HID;
  float4 h[4];
  float ss = 0.f;
#pragma unroll
  for (int i = 0; i < 4; ++i) {
    size_t idx = base + i * 1024 + tid * 4;
    float4 a = *(const float4*)(p0 + idx);
    float4 b = *(const float4*)(p1 + idx);
    float4 c = *(const float4*)(res + idx);
    h[i].x = a.x + b.x + c.x;
    h[i].y = a.y + b.y + c.y;
    h[i].z = a.z + b.z + c.z;
    h[i].w = a.w + b.w + c.w;
    *(float4*)(h2 + idx) = h[i];
    ss += h[i].x * h[i].x + h[i].y * h[i].y + h[i].z * h[i].z + h[i].w * h[i].w;
  }
#pragma unroll
  for (int m = 1; m < 64; m <<= 1) ss += __shfl_xor(ss, m);
  __shared__ float red[4];
  if ((tid & 63) == 0) red[tid >> 6] = ss;
  __syncthreads();
  float tot = red[0] + red[1] + red[2] + red[3];
  float rms = rsqrtf(tot / (float)HID + 1e-5f);
#pragma unroll
  for (int i = 0; i < 4; ++i) {
    int off = i * 1024 + tid * 4;
    ushort4 o;
    o.x = f2bf(h[i].x * rms * w[off + 0]);
    o.y = f2bf(h[i].y * rms * w[off + 1]);
    o.z = f2bf(h[i].z * rms * w[off + 2]);
    o.w = f2bf(h[i].w * rms * w[off + 3]);
    *(ushort4*)(xn2 + base + off) = o;
  }
}

// ---------------------------------------------------------------- GEMM direct-fp32-B
// C[M,N] = A[M,Kld](bf16,row) @ W[Kld,N](fp32,row)  — no pre-transpose.
// Tile 256x256; BK=64; 512 threads = 8 waves (2M x 4N).
// A: global_load_lds t+1 at ph1/ph2 (L2-resident, short latency OK).
// B: 32 coalesced dword loads per thread, TWO tiles ahead (ph3/ph4 of tile
// t issue B(t+2)) into ping-pong reg sets bvE/bvO; ph4 waits vmcnt(32) —
// drains B(t+1)+A(t+1), keeps B(t+2)'s 32 loads in flight (never 0).
// Loop unrolled x2 so reg-set selection is static (no scratch).
// EPI=0: bf16 -> Cv0. EPI=2: fp32 partial -> (s?Cv1:Cv0).
// EPI=3: bf16 silu(g)*acc -> Cv0, g read from Cv1 (bf16).
template <int EPI, int QKVSEL>
__global__ __launch_bounds__(512, 2) void gemmF_kernel(
    const unsigned short* __restrict__ A, const float* __restrict__ W0,
    const float* __restrict__ W1, const float* __restrict__ W2,
    void* __restrict__ Cv0, void* __restrict__ Cv1, int gridM, int N, int Kld,
    int nsplit) {
  constexpr int MF = 4;
  constexpr int ABYTES = 256 * 128;  // 32KB
  constexpr int BUFBYTES = ABYTES + 32768;
  __shared__ __align__(128) char sm[2 * BUFBYTES];

  const int tid  = threadIdx.x;
  const int lane = tid & 63;
  const int wv   = tid >> 6;
  const int nwg = gridDim.x;
  const int b = blockIdx.x;
  const int logical = (b & 7) * (nwg >> 3) + (b >> 3);
  const int ntiles = nwg / nsplit;
  const int s = logical / ntiles;
  const int r = logical - s * ntiles;
  const int m0 = (r % gridM) * 256;
  const int n0 = (r / gridM) * 256;
  const int Klen = Kld / nsplit;
  const int koff = s * Klen;
  const int wm = (wv >> 2) * 128;
  const int wn = (wv & 3) * 64;
  const int nt = Klen >> 6;

  // ---- B source select (uniform per block)
  const float* Bp;
  int Nw, bn0;
  if (QKVSEL) {
    if (n0 < 4096)      { Bp = W0; Nw = 4096; bn0 = n0; }
    else if (n0 < 5120) { Bp = W1; Nw = 1024; bn0 = n0 - 4096; }
    else                { Bp = W2; Nw = 1024; bn0 = n0 - 5120; }
  } else {
    Bp = W0; Nw = N; bn0 = n0;
  }

  // ---- A staging geometry (global_load_lds)
  const int srow = tid >> 3;
  const int scolb = (tid & 7) * 16;
  const int sldsbase = wv * 1024;  // HW adds lane*16
  auto stageA = [&](int half, int t) {
    char* ldsOp = sm + ((t & 1) * BUFBYTES);
    const int kt = koff + t * 64;
    const int rowBase = half * 128;
#pragma unroll
    for (int rr = 0; rr < 2; ++rr) {
      int row = rowBase + rr * 64 + srow;
      const char* gp = (const char*)A + ((size_t)(m0 + row) * Kld + kt) * 2 +
                       (scolb ^ ((row & 7) << 4));
      gload16(gp, ldsOp + rowBase * 128 + rr * 8192 + sldsbase);
    }
  };

  // ---- B reg staging: wave wv covers k-rows 8wv..8wv+7 (2 quads), lane
  // covers n = 64j + lane, j=0..3. Ping-pong sets (even/odd tiles).
  float bvE[2][4][4], bvO[2][4][4];
  auto loadBq = [&](float (&bv)[2][4][4], int q, int t) {
    const float* Wb = Bp + (size_t)(koff + t * 64 + wv * 8 + q * 4) * Nw +
                      bn0 + lane;
#pragma unroll
    for (int j = 0; j < 4; ++j)
#pragma unroll
      for (int ki = 0; ki < 4; ++ki)
        bv[q][j][ki] = Wb[(size_t)ki * Nw + 64 * j];
  };
  auto writeB = [&](const float (&bv)[2][4][4], char* sBw) {
#pragma unroll
    for (int q = 0; q < 2; ++q)
#pragma unroll
      for (int j = 0; j < 4; ++j) {
        int n = 64 * j + lane;
        int kq = wv * 8 + q * 4;
        uint2 pk;
        pk.x = (unsigned)f2bf(bv[q][j][0]) | ((unsigned)f2bf(bv[q][j][1]) << 16);
        pk.y = (unsigned)f2bf(bv[q][j][2]) | ((unsigned)f2bf(bv[q][j][3]) << 16);
        *(uint2*)(sBw + ((n * 128 + kq * 2) ^ ((n & 7) << 4))) = pk;
      }
  };

  const int kb0 = (lane >> 4) * 16;
  const int lrow = lane & 15;
  auto ldA = [&](const char* sA, int mh, int mf, int ks) {
    int row = wm + mh * 64 + mf * 16 + lrow;
    return *(const bf16x8*)(sA + ((row * 128 + kb0 + ks * 64) ^ ((row & 7) << 4)));
  };
  auto ldB = [&](const char* sB, int j, int ks) {
    int col = wn + j * 16 + lrow;
    return *(const bf16x8*)(sB + ((col * 128 + kb0 + ks * 64) ^ ((col & 7) << 4)));
  };

  f32x4 acc[2 * MF][4] = {};

  // ---- prologue: B(0)+A(0)+B(1); drain B(0)+A(0), keep B(1) in flight
  loadBq(bvE, 0, 0);
  loadBq(bvE, 1, 0);
  stageA(0, 0);
  stageA(1, 0);
  if (nt > 1) {
    loadBq(bvO, 0, 1);
    loadBq(bvO, 1, 1);
    asm volatile("s_waitcnt vmcnt(32)" ::: "memory");
  } else {
    asm volatile("s_waitcnt vmcnt(0)" ::: "memory");
  }
  writeB(bvE, sm + ABYTES);
  asm volatile("s_waitcnt lgkmcnt(0)" ::: "memory");
  __builtin_amdgcn_sched_barrier(0);
  __builtin_amdgcn_s_barrier();

  // ---- tile body: loads B(t+2) into bvL, writes B(t+1) from bvW at ph4
  auto tile_body = [&](int t, float (&bvL)[2][4][4],
                       const float (&bvW)[2][4][4]) {
    const char* sA = sm + (t & 1) * BUFBYTES;
    const char* sB = sA + ABYTES;
    char* sBw = sm + (((t & 1) ^ 1) * BUFBYTES) + ABYTES;
    const bool pfA = (t + 1 < nt);
    const bool pfB = (t + 2 < nt);
    bf16x8 a[MF], bb[4][2];

    // ---- phase 1: read B[ks0]+A(mh0,ks0); stage A-half0(t+1); MFMA
#pragma unroll
    for (int j = 0; j < 4; ++j) bb[j][0] = ldB(sB, j, 0);
#pragma unroll
    for (int mf = 0; mf < MF; ++mf) a[mf] = ldA(sA, 0, mf, 0);
    if (pfA) stageA(0, t + 1);
    __builtin_amdgcn_sched_barrier(0);
    __builtin_amdgcn_s_barrier();
    __builtin_amdgcn_s_setprio(1);
#pragma unroll
    for (int mf = 0; mf < MF; ++mf)
#pragma unroll
      for (int j = 0; j < 4; ++j)
        acc[mf][j] = __builtin_amdgcn_mfma_f32_16x16x32_bf16(
            a[mf], bb[j][0], acc[mf][j], 0, 0, 0);
    __builtin_amdgcn_s_setprio(0);
    __builtin_amdgcn_sched_barrier(0);
    __builtin_amdgcn_s_barrier();

    // ---- phase 2: read B[ks1]+A(mh0,ks1); stage A-half1(t+1); MFMA
#pragma unroll
    for (int j = 0; j < 4; ++j) bb[j][1] = ldB(sB, j, 1);
#pragma unroll
    for (int mf = 0; mf < MF; ++mf) a[mf] = ldA(sA, 0, mf, 1);
    if (pfA) stageA(1, t + 1);
    __builtin_amdgcn_sched_barrier(0);
    __builtin_amdgcn_s_barrier();
    __builtin_amdgcn_s_setprio(1);
#pragma unroll
    for (int mf = 0; mf < MF; ++mf)
#pragma unroll
      for (int j = 0; j < 4; ++j)
        acc[mf][j] = __builtin_amdgcn_mfma_f32_16x16x32_bf16(
            a[mf], bb[j][1], acc[mf][j], 0, 0, 0);
    __builtin_amdgcn_s_setprio(0);
    __builtin_amdgcn_sched_barrier(0);
    __builtin_amdgcn_s_barrier();

    // ---- phase 3: read A(mh1,ks0); issue B(t+2) quad0; MFMA
#pragma unroll
    for (int mf = 0; mf < MF; ++mf) a[mf] = ldA(sA, 1, mf, 0);
    if (pfB) loadBq(bvL, 0, t + 2);
    __builtin_amdgcn_sched_barrier(0);
    __builtin_amdgcn_s_barrier();
    __builtin_amdgcn_s_setprio(1);
#pragma unroll
    for (int mf = 0; mf < MF; ++mf)
#pragma unroll
      for (int j = 0; j < 4; ++j)
        acc[MF + mf][j] = __builtin_amdgcn_mfma_f32_16x16x32_bf16(
            a[mf], bb[j][0], acc[MF + mf][j], 0, 0, 0);
    __builtin_amdgcn_s_setprio(0);
    __builtin_amdgcn_sched_barrier(0);
    __builtin_amdgcn_s_barrier();

    // ---- phase 4: read A(mh1,ks1); issue B(t+2) quad1; counted drain;
    //      convert+write B(t+1); MFMA
#pragma unroll
    for (int mf = 0; mf < MF; ++mf) a[mf] = ldA(sA, 1, mf, 1);
    if (pfB) {
      loadBq(bvL, 1, t + 2);
      asm volatile("s_waitcnt vmcnt(32)" ::: "memory");
    } else {
      asm volatile("s_waitcnt vmcnt(0)" ::: "memory");
    }
    if (pfA) writeB(bvW, sBw);
    asm volatile("s_waitcnt lgkmcnt(0)" ::: "memory");
    __builtin_amdgcn_sched_barrier(0);
    __builtin_amdgcn_s_barrier();
    __builtin_amdgcn_s_setprio(1);
#pragma unroll
    for (int mf = 0; mf < MF; ++mf)
#pragma unroll
      for (int j = 0; j < 4; ++j)
        acc[MF + mf][j] = __builtin_amdgcn_mfma_f32_16x16x32_bf16(
            a[mf], bb[j][1], acc[MF + mf][j], 0, 0, 0);
    __builtin_amdgcn_s_setprio(0);
    __builtin_amdgcn_sched_barrier(0);
    __builtin_amdgcn_s_barrier();
  };

  for (int t = 0; t < nt; t += 2) {
    tile_body(t, bvE, bvO);
    if (t + 1 < nt) tile_body(t + 1, bvO, bvE);
  }

  // ---- epilogue
  const int rb = (lane >> 4) * 4;
  float* P = (float*)(s ? Cv1 : Cv0);
#pragma unroll
  for (int i = 0; i < 2 * MF; ++i) {
    const int mh = i / MF, mf = i % MF;
#pragma unroll
    for (int j = 0; j < 4; ++j) {
#pragma unroll
      for (int rr = 0; rr < 4; ++rr) {
        size_t row = (size_t)(m0 + wm + mh * 64 + mf * 16 + rb + rr);
        size_t col = (size_t)(n0 + wn + j * 16 + lrow);
        float vv = acc[i][j][rr];
        if (EPI == 0) {
          ((unsigned short*)Cv0)[row * N + col] = f2bf(vv);
        } else if (EPI == 2) {
          P[row * N + col] = vv;
        } else {  // EPI == 3: silu(g) * acc
          float g = bf2f(((const unsigned short*)Cv1)[row * N + col]);
          float sl = g / (1.f + __expf(-g));
          ((unsigned short*)Cv0)[row * N + col] = f2bf(sl * vv);
        }
      }
    }
  }
}

// ---------------------------------------------------------------- Flash attention
// grid 512 x 512 threads. Block = 128 q-rows x 1 head, 8 waves x 16 rows.
__global__ __launch_bounds__(512, 1) void attn_kernel(
    const unsigned short* __restrict__ QKV, unsigned short* __restrict__ Ob) {
  __shared__ __align__(128) char sm[114688];
  char* sQ  = sm;
  char* sK0 = sm + 32768;
  char* sK1 = sm + 49152;
  char* sV0 = sm + 65536;
  char* sV1 = sm + 81920;
  char* sP  = sm + 98304;
  const int tid  = threadIdx.x;
  const int lane = tid & 63;
  const int wv   = tid >> 6;
  const int logical = blockIdx.x;
  const int xr = 15 - (logical >> 5);
  const int h = logical & 31;
  const int qb0 = xr * 128;
  const int hkv = h >> 2;
  const int rbase = (lane >> 4) * 4;
  const int cbase = lane & 15;
  const unsigned short* Qp = QKV + h * DH;
  const unsigned short* Kp = QKV + NH * DH + hkv * DH;
  const unsigned short* Vp = QKV + NH * DH + NKV * DH + hkv * DH;

#pragma unroll
  for (int i = 0; i < 4; ++i) {
    int offs = i * 8192 + tid * 16;
    int row = offs >> 8, col = offs & 255;
    const char* gp = (const char*)Qp + ((size_t)(qb0 + row) * QKVN) * 2 +
                     (col ^ ((row & 15) << 4));
    gload16(gp, sQ + i * 8192 + wv * 1024);
  }

  auto stageK = [&](int t) {
    char* dst = (t & 1) ? sK1 : sK0;
    const int kt0 = t * 64;
#pragma unroll
    for (int i = 0; i < 2; ++i) {
      int offs = i * 8192 + tid * 16;
      int row = offs >> 8, col = offs & 255;
      const char* gp = (const char*)Kp + ((size_t)(kt0 + row) * QKVN) * 2 +
                       (col ^ ((row & 15) << 4));
      gload16(gp, dst + i * 8192 + wv * 1024);
    }
  };

  const int d4  = (tid & 31) * 4;
  const int kv4 = (tid >> 5) * 4;
  const int rot = (tid >> 1) & 3;
  auto loadV = [&](int t, ushort4* vr) {
    const unsigned short* g0 = Vp + (size_t)(t * 64 + kv4) * QKVN + d4;
#pragma unroll
    for (int k = 0; k < 4; ++k) vr[k] = *(const ushort4*)(g0 + (size_t)k * QKVN);
  };
  auto writeV = [&](int t, const ushort4* vr) {
    char* dst = (t & 1) ? sV1 : sV0;
    const unsigned short* a0 = (const unsigned short*)&vr[0];
    const unsigned short* a1 = (const unsigned short*)&vr[1];
    const unsigned short* a2 = (const unsigned short*)&vr[2];
    const unsigned short* a3 = (const unsigned short*)&vr[3];
#pragma unroll
    for (int j = 0; j < 4; ++j) {
      int jj = (j + rot) & 3;
      int dd = d4 + jj;
      uint2 pk;
      pk.x = (unsigned)a0[jj] | ((unsigned)a1[jj] << 16);
      pk.y = (unsigned)a2[jj] | ((unsigned)a3[jj] << 16);
      *(uint2*)(dst + ((dd * 128 + kv4 * 2) ^ ((dd & 7) << 4))) = pk;
    }
  };

  ushort4 vr[4];
  stageK(0);
  loadV(0, vr);
  asm volatile("s_waitcnt vmcnt(0)" ::: "memory");
  writeV(0, vr);
  __syncthreads();

  const int qrow = wv * 16 + (lane & 15);
  bf16x8 aq[4];
#pragma unroll
  for (int kk = 0; kk < 4; ++kk) {
    int kb = (lane >> 4) * 16 + kk * 64;
    aq[kk] = *(const bf16x8*)(sQ + ((qrow * 256 + kb) ^ ((qrow & 15) << 4)));
  }

  f32x4 oacc[8] = {};
  float m_r[4] = {-1e30f, -1e30f, -1e30f, -1e30f};
  float l_r[4] = {0.f, 0.f, 0.f, 0.f};
  const int ntiles = 2 * (xr + 1);

  for (int t = 0; t < ntiles; ++t) {
    const int kt0 = t * 64;
    const char* cK = (t & 1) ? sK1 : sK0;
    const char* cV = (t & 1) ? sV1 : sV0;
    if (t + 1 < ntiles) {
      stageK(t + 1);
      loadV(t + 1, vr);
    }

    f32x4 sacc[4] = {};
#pragma unroll
    for (int kk = 0; kk < 4; ++kk) {
      int kb = (lane >> 4) * 16 + kk * 64;
#pragma unroll
      for (int ni = 0; ni < 4; ++ni) {
        int krow = ni * 16 + (lane & 15);
        bf16x8 bk =
            *(const bf16x8*)(cK + ((krow * 256 + kb) ^ ((krow & 15) << 4)));
        sacc[ni] = __builtin_amdgcn_mfma_f32_16x16x32_bf16(aq[kk], bk,
                                                           sacc[ni], 0, 0, 0);
      }
    }

    const float scale = 0.08838834764831845f;
#pragma unroll
    for (int r = 0; r < 4; ++r) {
      int qg = qb0 + wv * 16 + rbase + r;
      float mx = -1e30f;
#pragma unroll
      for (int ni = 0; ni < 4; ++ni) {
        int cg = kt0 + ni * 16 + cbase;
        float sv = sacc[ni][r] * scale;
        sv = (cg <= qg) ? sv : -1e30f;
        sacc[ni][r] = sv;
        mx = fmaxf(mx, sv);
      }
      mx = fmaxf(mx, __shfl_xor(mx, 1));
      mx = fmaxf(mx, __shfl_xor(mx, 2));
      mx = fmaxf(mx, __shfl_xor(mx, 4));
      mx = fmaxf(mx, __shfl_xor(mx, 8));
      float mnew = fmaxf(m_r[r], mx);
      float sf = __expf(m_r[r] - mnew);
      m_r[r] = mnew;
      float rsum = 0.f;
#pragma unroll
      for (int ni = 0; ni < 4; ++ni) {
        float pv = __expf(sacc[ni][r] - mnew);
        sacc[ni][r] = pv;
        rsum += pv;
      }
      rsum += __shfl_xor(rsum, 1);
      rsum += __shfl_xor(rsum, 2);
      rsum += __shfl_xor(rsum, 4);
      rsum += __shfl_xor(rsum, 8);
      l_r[r] = l_r[r] * sf + rsum;
#pragma unroll
      for (int nt2 = 0; nt2 < 8; ++nt2) oacc[nt2][r] *= sf;
    }

    char* pw = sP + wv * 2048;
#pragma unroll
    for (int ni = 0; ni < 4; ++ni)
#pragma unroll
      for (int r = 0; r < 4; ++r) {
        int row = rbase + r;
        int cb2 = (ni * 16 + cbase) * 2;
        *(unsigned short*)(pw + ((row * 128 + cb2) ^ ((row & 7) << 4))) =
            f2bf(sacc[ni][r]);
      }
    asm volatile("s_waitcnt lgkmcnt(0)" ::: "memory");

#pragma unroll
    for (int kk = 0; kk < 2; ++kk) {
      int kb = (lane >> 4) * 16 + kk * 64;
      int prow = lane & 15;
      bf16x8 ap =
          *(const bf16x8*)(pw + ((prow * 128 + kb) ^ ((prow & 7) << 4)));
#pragma unroll
      for (int nt2 = 0; nt2 < 8; ++nt2) {
        int vrow = nt2 * 16 + (lane & 15);
        bf16x8 bv2 =
            *(const bf16x8*)(cV + ((vrow * 128 + kb) ^ ((vrow & 7) << 4)));
        oacc[nt2] =
            __builtin_amdgcn_mfma_f32_16x16x32_bf16(ap, bv2, oacc[nt2], 0, 0, 0);
      }
    }

    if (t + 1 < ntiles) {
      asm volatile("s_waitcnt vmcnt(0)" ::: "memory");
      writeV(t + 1, vr);
    }
    __syncthreads();
  }

#pragma unroll
  for (int nt2 = 0; nt2 < 8; ++nt2)
#pragma unroll
    for (int r = 0; r < 4; ++r) {
      size_t row = (size_t)(qb0 + wv * 16 + rbase + r);
      int col = nt2 * 16 + cbase;
      Ob[row * (NH * DH) + h * DH + col] = f2bf(oacc[nt2][r] / l_r[r]);
    }
}

// ---------------------------------------------------------------- host
extern "C" void kernel_launch(void* const* d_in, const int* in_sizes, int n_in,
                              void* d_out, int out_size, void* d_ws,
                              size_t ws_size, hipStream_t stream) {
  const float* hs  = (const float*)d_in[0];
  const float* wq  = (const float*)d_in[1];
  const float* wk  = (const float*)d_in[2];
  const float* wvp = (const float*)d_in[3];
  const float* wo  = (const float*)d_in[4];
  const float* wg  = (const float*)d_in[5];
  const float* wu  = (const float*)d_in[6];
  const float* wd  = (const float*)d_in[7];
  const float* ln1 = (const float*)d_in[8];
  const float* ln2 = (const float*)d_in[9];

  char* p = (char*)d_ws;
  size_t need = 0;
  auto alloc = [&](size_t bytes) {
    char* r = p + need;
    need += (bytes + 255) & ~(size_t)255;
    return r;
  };
  unsigned short* xn   = (unsigned short*)alloc((size_t)SEQ * HID * 2);
  unsigned short* qkv  = (unsigned short*)alloc((size_t)SEQ * QKVN * 2);
  unsigned short* ab   = (unsigned short*)alloc((size_t)SEQ * NH * DH * 2);
  float*          h2   = (float*)alloc((size_t)SEQ * HID * 4);
  unsigned short* xn2  = (unsigned short*)alloc((size_t)SEQ * HID * 2);
  unsigned short* gbuf = (unsigned short*)alloc((size_t)SEQ * FF * 2);
  float*          pA   = (float*)alloc((size_t)SEQ * HID * 4);
  float*          pB   = (float*)alloc((size_t)SEQ * HID * 4);
  if (need > ws_size) return;  // workspace too small: fail visibly

  // 1) rmsnorm1
  rmsnorm_kernel<<<SEQ, 256, 0, stream>>>(hs, ln1, xn);
  // 2) fused qkv projection, fp32 weights direct (grid 8*24=192)
  gemmF_kernel<0, 1><<<(SEQ / 256) * (QKVN / 256), 512, 0, stream>>>(
      xn, wq, wk, wvp, qkv, nullptr, SEQ / 256, QKVN, HID, 1);
  // 3) RoPE
  rope_kernel<<<(SEQ * NH * 64) / 256, 256, 0, stream>>>(qkv, NH, QKVN);
  rope_kernel<<<(SEQ * NKV * 64) / 256, 256, 0, stream>>>(qkv + NH * DH, NKV,
                                                          QKVN);
  // 4) attention (512 blocks, LPT)
  attn_kernel<<<512, 512, 0, stream>>>(qkv, ab);
  // 5) o-proj split-K=2 (grid 256) + fused combine+rmsnorm2 -> h2, xn2
  gemmF_kernel<2, 0><<<256, 512, 0, stream>>>(ab, wo, nullptr, nullptr, pA, pB,
                                              SEQ / 256, HID, HID, 2);
  combine_rms_kernel<<<SEQ, 256, 0, stream>>>(pA, pB, hs, ln2, h2, xn2);
  // 6) gate (grid 448)
  gemmF_kernel<0, 0><<<(SEQ / 256) * (FF / 256), 512, 0, stream>>>(
      xn2, wg, nullptr, nullptr, gbuf, nullptr, SEQ / 256, FF, HID, 1);
  // 7) up with fused SiLU epilogue (reads gate from gbuf, writes in place)
  gemmF_kernel<3, 0><<<(SEQ / 256) * (FF / 256), 512, 0, stream>>>(
      xn2, wu, nullptr, nullptr, gbuf, gbuf, SEQ / 256, FF, HID, 1);
  // 8) down-proj split-K=2 (grid 256) + combine with residual h2 -> out
  gemmF_kernel<2, 0><<<256, 512, 0, stream>>>(gbuf, wd, nullptr, nullptr, pA,
                                              pB, SEQ / 256, HID, FF, 2);
  combine_kernel<<<(SEQ * HID) / 1024, 256, 0, stream>>>(pA, pB, h2,
                                                         (float*)d_out);
}

// Round 10
// 1296.373 us; speedup vs baseline: 68.9059x; 68.9059x over previous
//
#include <hip/hip_runtime.h>

typedef short bf16x8 __attribute__((ext_vector_type(8)));
typedef float f32x4 __attribute__((ext_vector_type(4)));

#define DEV __device__ __forceinline__

constexpr int SEQ = 2048;
constexpr int HID = 4096;
constexpr int NH  = 32;
constexpr int NKV = 8;
constexpr int DH  = 128;
constexpr int FF  = 14336;
constexpr int QKVN = NH * DH + 2 * NKV * DH;  // 6144

DEV unsigned short f2bf(float f) {
  union { float f; unsigned u; } x; x.f = f;
  unsigned r = x.u + 0x7fffu + ((x.u >> 16) & 1u);
  return (unsigned short)(r >> 16);
}
DEV float bf2f(unsigned short u) {
  union { unsigned u; float f; } x; x.u = ((unsigned)u) << 16; return x.f;
}
DEV void gload16(const void* g, void* l) {
  __builtin_amdgcn_global_load_lds(
      (const __attribute__((address_space(1))) unsigned*)g,
      (__attribute__((address_space(3))) unsigned*)l, 16, 0, 0);
}

// ---------------------------------------------------------------- RMSNorm
__global__ __launch_bounds__(256) void rmsnorm_kernel(
    const float* __restrict__ x, const float* __restrict__ w,
    unsigned short* __restrict__ out) {
  const int row = blockIdx.x;
  const int tid = threadIdx.x;
  const float* xr = x + (size_t)row * HID;
  float4 v[4];
  float ss = 0.f;
#pragma unroll
  for (int i = 0; i < 4; ++i) {
    v[i] = *(const float4*)(xr + i * 1024 + tid * 4);
    ss += v[i].x * v[i].x + v[i].y * v[i].y + v[i].z * v[i].z + v[i].w * v[i].w;
  }
#pragma unroll
  for (int m = 1; m < 64; m <<= 1) ss += __shfl_xor(ss, m);
  __shared__ float red[4];
  if ((tid & 63) == 0) red[tid >> 6] = ss;
  __syncthreads();
  float tot = red[0] + red[1] + red[2] + red[3];
  float rms = rsqrtf(tot / (float)HID + 1e-5f);
  unsigned short* orow = out + (size_t)row * HID;
#pragma unroll
  for (int i = 0; i < 4; ++i) {
    int base = i * 1024 + tid * 4;
    ushort4 o;
    o.x = f2bf(v[i].x * rms * w[base + 0]);
    o.y = f2bf(v[i].y * rms * w[base + 1]);
    o.z = f2bf(v[i].z * rms * w[base + 2]);
    o.w = f2bf(v[i].w * rms * w[base + 3]);
    *(ushort4*)(orow + base) = o;
  }
}

// ------------------------------------------------- weight transpose+convert
// W[K][N] fp32 -> WT[N][K] bf16. grid (K/64, N/64), 256 threads.
__global__ __launch_bounds__(256) void wtrans_kernel(
    const float* __restrict__ W, unsigned short* __restrict__ WT, int K,
    int N) {
  __shared__ unsigned short t[64][72];
  const int k0 = blockIdx.x * 64, n0 = blockIdx.y * 64;
  const int tid = threadIdx.x;
  const int tk = tid >> 4;
  const int tn4 = (tid & 15) * 4;
#pragma unroll
  for (int p = 0; p < 4; ++p) {
    int k = tk + p * 16;
    float4 v = *(const float4*)(W + (size_t)(k0 + k) * N + n0 + tn4);
    t[tn4 + 0][k] = f2bf(v.x);
    t[tn4 + 1][k] = f2bf(v.y);
    t[tn4 + 2][k] = f2bf(v.z);
    t[tn4 + 3][k] = f2bf(v.w);
  }
  __syncthreads();
#pragma unroll
  for (int p = 0; p < 4; ++p) {
    int n = tk + p * 16;
    ushort4 o = *(const ushort4*)&t[n][tn4];
    *(ushort4*)(WT + (size_t)(n0 + n) * K + k0 + tn4) = o;
  }
}

// ---------------------------------------------------------------- RoPE (in-place, strided)
__global__ __launch_bounds__(256) void rope_kernel(unsigned short* __restrict__ x,
                                                   int nheads, int ld) {
  const int gid = blockIdx.x * 256 + threadIdx.x;
  const int i = gid & 63;
  const int t = gid >> 6;
  const int s = t / nheads;
  const int hh = t - s * nheads;
  float ang = (float)s * exp2f((float)i * (-29.897352853986263f / 64.f));
  float sn, cs;
  sincosf(ang, &sn, &cs);
  size_t base = (size_t)s * ld + hh * DH + i;
  float x1 = bf2f(x[base]);
  float x2 = bf2f(x[base + 64]);
  x[base]      = f2bf(x1 * cs - x2 * sn);
  x[base + 64] = f2bf(x2 * cs + x1 * sn);
}

// ---------------------------------------------------------------- combine (final)
__global__ __launch_bounds__(256) void combine_kernel(
    const float* __restrict__ p0, const float* __restrict__ p1,
    const float* __restrict__ res, float* __restrict__ out) {
  const size_t i = ((size_t)blockIdx.x * 256 + threadIdx.x) * 4;
  float4 a = *(const float4*)(p0 + i);
  float4 b = *(const float4*)(p1 + i);
  float4 c = *(const float4*)(res + i);
  float4 o;
  o.x = a.x + b.x + c.x;
  o.y = a.y + b.y + c.y;
  o.z = a.z + b.z + c.z;
  o.w = a.w + b.w + c.w;
  *(float4*)(out + i) = o;
}

// ---------------------------------------------------------------- combine + rmsnorm
__global__ __launch_bounds__(256) void combine_rms_kernel(
    const float* __restrict__ p0, const float* __restrict__ p1,
    const float* __restrict__ res, const float* __restrict__ w,
    float* __restrict__ h2, unsigned short* __restrict__ xn2) {
  const int row = blockIdx.x;
  const int tid = threadIdx.x;
  const size_t base = (size_t)row * HID;
  float4 h[4];
  float ss = 0.f;
#pragma unroll
  for (int i = 0; i < 4; ++i) {
    size_t idx = base + i * 1024 + tid * 4;
    float4 a = *(const float4*)(p0 + idx);
    float4 b = *(const float4*)(p1 + idx);
    float4 c = *(const float4*)(res + idx);
    h[i].x = a.x + b.x + c.x;
    h[i].y = a.y + b.y + c.y;
    h[i].z = a.z + b.z + c.z;
    h[i].w = a.w + b.w + c.w;
    *(float4*)(h2 + idx) = h[i];
    ss += h[i].x * h[i].x + h[i].y * h[i].y + h[i].z * h[i].z + h[i].w * h[i].w;
  }
#pragma unroll
  for (int m = 1; m < 64; m <<= 1) ss += __shfl_xor(ss, m);
  __shared__ float red[4];
  if ((tid & 63) == 0) red[tid >> 6] = ss;
  __syncthreads();
  float tot = red[0] + red[1] + red[2] + red[3];
  float rms = rsqrtf(tot / (float)HID + 1e-5f);
#pragma unroll
  for (int i = 0; i < 4; ++i) {
    int off = i * 1024 + tid * 4;
    ushort4 o;
    o.x = f2bf(h[i].x * rms * w[off + 0]);
    o.y = f2bf(h[i].y * rms * w[off + 1]);
    o.z = f2bf(h[i].z * rms * w[off + 2]);
    o.w = f2bf(h[i].w * rms * w[off + 3]);
    *(ushort4*)(xn2 + base + off) = o;
  }
}

// ---------------------------------------------------------------- GEMM 8-phase (fat)
// C[M,N] = A[M,Kld](bf16,row) @ BT[N,Kld](bf16,row)^T, optional split-K.
// Tile 256x256; BK=64; 512 threads = 8 waves (2M x 4N).
// Fat co-schedule: blocks [0, n_t) run a grid-stride weight transpose
// TW[TK][TN] fp32 -> TWT[TN][TK] bf16 FIRST (dense BW prelude, not a
// straggler tail); GEMM blocks are blockIdx - n_t.
// EPI=0: bf16 -> Cv0.  EPI=2: fp32 partial -> (s?Cv1:Cv0).
// EPI=3: bf16 silu(g)*acc -> Cv0, g read from Cv1 (bf16).
template <int EPI>
__global__ __launch_bounds__(512, 2) void gemm8p_kernel(
    const unsigned short* __restrict__ A, const unsigned short* __restrict__ BT,
    void* __restrict__ Cv0, void* __restrict__ Cv1, int gridM, int N, int Kld,
    int nsplit, const float* __restrict__ TW, unsigned short* __restrict__ TWT,
    int TK, int TN, int n_t) {
  constexpr int MF = 4;
  constexpr int ABYTES = 256 * 128;  // 32KB
  constexpr int BUFBYTES = ABYTES + 32768;
  __shared__ __align__(128) char sm[2 * BUFBYTES];

  const int tid = threadIdx.x;
  const int nwg = gridDim.x - n_t;

  if ((int)blockIdx.x < n_t) {
    // ---------------- transpose path (2 teams of 256 threads)
    const int team = tid >> 8, lt = tid & 255;
    unsigned short(*tt)[72] = (unsigned short(*)[72])(sm + team * 9216);
    const int tilesK = TK >> 6;
    const int tot = tilesK * (TN >> 6);
    const int tk = lt >> 4;
    const int tn4 = (lt & 15) * 4;
    for (int tile = (int)blockIdx.x * 2 + team; tile < tot; tile += n_t * 2) {
      const int k0 = (tile % tilesK) << 6;
      const int n0t = (tile / tilesK) << 6;
#pragma unroll
      for (int p = 0; p < 4; ++p) {
        int k = tk + p * 16;
        float4 v = *(const float4*)(TW + (size_t)(k0 + k) * TN + n0t + tn4);
        tt[tn4 + 0][k] = f2bf(v.x);
        tt[tn4 + 1][k] = f2bf(v.y);
        tt[tn4 + 2][k] = f2bf(v.z);
        tt[tn4 + 3][k] = f2bf(v.w);
      }
      __syncthreads();
#pragma unroll
      for (int p = 0; p < 4; ++p) {
        int n = tk + p * 16;
        ushort4 o = *(const ushort4*)&tt[n][tn4];
        *(ushort4*)(TWT + (size_t)(n0t + n) * TK + k0 + tn4) = o;
      }
      __syncthreads();
    }
    return;
  }

  // ---------------- GEMM path
  const int lane = tid & 63;
  const int wv   = tid >> 6;
  const int b = (int)blockIdx.x - n_t;
  const int logical = (b & 7) * (nwg >> 3) + (b >> 3);
  const int ntiles = nwg / nsplit;
  const int s = logical / ntiles;
  const int r = logical - s * ntiles;
  const int m0 = (r % gridM) * 256;
  const int n0 = (r / gridM) * 256;
  const int Klen = Kld / nsplit;
  const int koff = s * Klen;
  const int wm = (wv >> 2) * 128;
  const int wn = (wv & 3) * 64;
  const int nt = Klen >> 6;

  const int srow = tid >> 3;
  const int scolb = (tid & 7) * 16;
  const int sldsbase = wv * 1024;  // HW adds lane*16

  auto stage = [&](int h, int t) {
    const int buf = t & 1;
    const int kt = koff + t * 64;
    char* ldsOp;
    const unsigned short* g;
    int grow0, rowBase;
    if (h < 2) {
      ldsOp = sm + buf * BUFBYTES + ABYTES; g = BT; grow0 = n0; rowBase = h * 128;
    } else {
      ldsOp = sm + buf * BUFBYTES;          g = A;  grow0 = m0; rowBase = (h - 2) * 128;
    }
#pragma unroll
    for (int rr = 0; rr < 2; ++rr) {
      int row = rowBase + rr * 64 + srow;
      const char* gp = (const char*)g + ((size_t)(grow0 + row) * Kld + kt) * 2 +
                       (scolb ^ ((row & 7) << 4));
      gload16(gp, ldsOp + rowBase * 128 + rr * 8192 + sldsbase);
    }
  };

  const int kb0 = (lane >> 4) * 16;
  const int lrow = lane & 15;
  auto ldA = [&](const char* sA, int mh, int mf, int ks) {
    int row = wm + mh * 64 + mf * 16 + lrow;
    return *(const bf16x8*)(sA + ((row * 128 + kb0 + ks * 64) ^ ((row & 7) << 4)));
  };
  auto ldB = [&](const char* sB, int j, int ks) {
    int col = wn + j * 16 + lrow;
    return *(const bf16x8*)(sB + ((col * 128 + kb0 + ks * 64) ^ ((col & 7) << 4)));
  };

  f32x4 acc[2 * MF][4] = {};

  stage(2, 0); stage(3, 0); stage(0, 0); stage(1, 0);
  if (nt > 1) {
    stage(0, 1); stage(1, 1);
    asm volatile("s_waitcnt vmcnt(4)" ::: "memory");
  } else {
    asm volatile("s_waitcnt vmcnt(0)" ::: "memory");
  }
  __builtin_amdgcn_s_barrier();

  for (int t = 0; t < nt; ++t) {
    const char* sA = sm + (t & 1) * BUFBYTES;
    const char* sB = sA + ABYTES;
    bf16x8 a[MF], bb[4][2];

#pragma unroll
    for (int j = 0; j < 4; ++j) bb[j][0] = ldB(sB, j, 0);
#pragma unroll
    for (int mf = 0; mf < MF; ++mf) a[mf] = ldA(sA, 0, mf, 0);
    if (t + 1 < nt) stage(2, t + 1);
    __builtin_amdgcn_sched_barrier(0);
    __builtin_amdgcn_s_barrier();
    __builtin_amdgcn_s_setprio(1);
#pragma unroll
    for (int mf = 0; mf < MF; ++mf)
#pragma unroll
      for (int j = 0; j < 4; ++j)
        acc[mf][j] = __builtin_amdgcn_mfma_f32_16x16x32_bf16(
            a[mf], bb[j][0], acc[mf][j], 0, 0, 0);
    __builtin_amdgcn_s_setprio(0);
    __builtin_amdgcn_sched_barrier(0);
    __builtin_amdgcn_s_barrier();

#pragma unroll
    for (int j = 0; j < 4; ++j) bb[j][1] = ldB(sB, j, 1);
#pragma unroll
    for (int mf = 0; mf < MF; ++mf) a[mf] = ldA(sA, 0, mf, 1);
    if (t + 1 < nt) stage(3, t + 1);
    __builtin_amdgcn_sched_barrier(0);
    __builtin_amdgcn_s_barrier();
    __builtin_amdgcn_s_setprio(1);
#pragma unroll
    for (int mf = 0; mf < MF; ++mf)
#pragma unroll
      for (int j = 0; j < 4; ++j)
        acc[mf][j] = __builtin_amdgcn_mfma_f32_16x16x32_bf16(
            a[mf], bb[j][1], acc[mf][j], 0, 0, 0);
    __builtin_amdgcn_s_setprio(0);
    __builtin_amdgcn_sched_barrier(0);
    __builtin_amdgcn_s_barrier();

#pragma unroll
    for (int mf = 0; mf < MF; ++mf) a[mf] = ldA(sA, 1, mf, 0);
    if (t + 2 < nt) stage(0, t + 2);
    __builtin_amdgcn_sched_barrier(0);
    __builtin_amdgcn_s_barrier();
    __builtin_amdgcn_s_setprio(1);
#pragma unroll
    for (int mf = 0; mf < MF; ++mf)
#pragma unroll
      for (int j = 0; j < 4; ++j)
        acc[MF + mf][j] = __builtin_amdgcn_mfma_f32_16x16x32_bf16(
            a[mf], bb[j][0], acc[MF + mf][j], 0, 0, 0);
    __builtin_amdgcn_s_setprio(0);
    __builtin_amdgcn_sched_barrier(0);
    __builtin_amdgcn_s_barrier();

#pragma unroll
    for (int mf = 0; mf < MF; ++mf) a[mf] = ldA(sA, 1, mf, 1);
    if (t + 2 < nt) {
      stage(1, t + 2);
      asm volatile("s_waitcnt vmcnt(4)" ::: "memory");
    } else {
      asm volatile("s_waitcnt vmcnt(0)" ::: "memory");
    }
    __builtin_amdgcn_sched_barrier(0);
    __builtin_amdgcn_s_barrier();
    __builtin_amdgcn_s_setprio(1);
#pragma unroll
    for (int mf = 0; mf < MF; ++mf)
#pragma unroll
      for (int j = 0; j < 4; ++j)
        acc[MF + mf][j] = __builtin_amdgcn_mfma_f32_16x16x32_bf16(
            a[mf], bb[j][1], acc[MF + mf][j], 0, 0, 0);
    __builtin_amdgcn_s_setprio(0);
    __builtin_amdgcn_sched_barrier(0);
    __builtin_amdgcn_s_barrier();
  }

  const int rb = (lane >> 4) * 4;
  float* P = (float*)(s ? Cv1 : Cv0);
#pragma unroll
  for (int i = 0; i < 2 * MF; ++i) {
    const int mh = i / MF, mf = i % MF;
#pragma unroll
    for (int j = 0; j < 4; ++j) {
#pragma unroll
      for (int rr = 0; rr < 4; ++rr) {
        size_t row = (size_t)(m0 + wm + mh * 64 + mf * 16 + rb + rr);
        size_t col = (size_t)(n0 + wn + j * 16 + lrow);
        float vv = acc[i][j][rr];
        if (EPI == 0) {
          ((unsigned short*)Cv0)[row * N + col] = f2bf(vv);
        } else if (EPI == 2) {
          P[row * N + col] = vv;
        } else {  // EPI == 3: silu(g) * acc
          float g = bf2f(((const unsigned short*)Cv1)[row * N + col]);
          float sl = g / (1.f + __expf(-g));
          ((unsigned short*)Cv0)[row * N + col] = f2bf(sl * vv);
        }
      }
    }
  }
}

// ---------------------------------------------------------------- Flash attention
// grid 512 x 512 threads. Block = 128 q-rows x 1 head, 8 waves x 16 rows.
__global__ __launch_bounds__(512, 1) void attn_kernel(
    const unsigned short* __restrict__ QKV, unsigned short* __restrict__ Ob) {
  __shared__ __align__(128) char sm[114688];
  char* sQ  = sm;
  char* sK0 = sm + 32768;
  char* sK1 = sm + 49152;
  char* sV0 = sm + 65536;
  char* sV1 = sm + 81920;
  char* sP  = sm + 98304;
  const int tid  = threadIdx.x;
  const int lane = tid & 63;
  const int wv   = tid >> 6;
  const int logical = blockIdx.x;
  const int xr = 15 - (logical >> 5);
  const int h = logical & 31;
  const int qb0 = xr * 128;
  const int hkv = h >> 2;
  const int rbase = (lane >> 4) * 4;
  const int cbase = lane & 15;
  const unsigned short* Qp = QKV + h * DH;
  const unsigned short* Kp = QKV + NH * DH + hkv * DH;
  const unsigned short* Vp = QKV + NH * DH + NKV * DH + hkv * DH;

#pragma unroll
  for (int i = 0; i < 4; ++i) {
    int offs = i * 8192 + tid * 16;
    int row = offs >> 8, col = offs & 255;
    const char* gp = (const char*)Qp + ((size_t)(qb0 + row) * QKVN) * 2 +
                     (col ^ ((row & 15) << 4));
    gload16(gp, sQ + i * 8192 + wv * 1024);
  }

  auto stageK = [&](int t) {
    char* dst = (t & 1) ? sK1 : sK0;
    const int kt0 = t * 64;
#pragma unroll
    for (int i = 0; i < 2; ++i) {
      int offs = i * 8192 + tid * 16;
      int row = offs >> 8, col = offs & 255;
      const char* gp = (const char*)Kp + ((size_t)(kt0 + row) * QKVN) * 2 +
                       (col ^ ((row & 15) << 4));
      gload16(gp, dst + i * 8192 + wv * 1024);
    }
  };

  const int d4  = (tid & 31) * 4;
  const int kv4 = (tid >> 5) * 4;
  const int rot = (tid >> 1) & 3;
  auto loadV = [&](int t, ushort4* vr) {
    const unsigned short* g0 = Vp + (size_t)(t * 64 + kv4) * QKVN + d4;
#pragma unroll
    for (int k = 0; k < 4; ++k) vr[k] = *(const ushort4*)(g0 + (size_t)k * QKVN);
  };
  auto writeV = [&](int t, const ushort4* vr) {
    char* dst = (t & 1) ? sV1 : sV0;
    const unsigned short* a0 = (const unsigned short*)&vr[0];
    const unsigned short* a1 = (const unsigned short*)&vr[1];
    const unsigned short* a2 = (const unsigned short*)&vr[2];
    const unsigned short* a3 = (const unsigned short*)&vr[3];
#pragma unroll
    for (int j = 0; j < 4; ++j) {
      int jj = (j + rot) & 3;
      int dd = d4 + jj;
      uint2 pk;
      pk.x = (unsigned)a0[jj] | ((unsigned)a1[jj] << 16);
      pk.y = (unsigned)a2[jj] | ((unsigned)a3[jj] << 16);
      *(uint2*)(dst + ((dd * 128 + kv4 * 2) ^ ((dd & 7) << 4))) = pk;
    }
  };

  ushort4 vr[4];
  stageK(0);
  loadV(0, vr);
  asm volatile("s_waitcnt vmcnt(0)" ::: "memory");
  writeV(0, vr);
  __syncthreads();

  const int qrow = wv * 16 + (lane & 15);
  bf16x8 aq[4];
#pragma unroll
  for (int kk = 0; kk < 4; ++kk) {
    int kb = (lane >> 4) * 16 + kk * 64;
    aq[kk] = *(const bf16x8*)(sQ + ((qrow * 256 + kb) ^ ((qrow & 15) << 4)));
  }

  f32x4 oacc[8] = {};
  float m_r[4] = {-1e30f, -1e30f, -1e30f, -1e30f};
  float l_r[4] = {0.f, 0.f, 0.f, 0.f};
  const int ntiles = 2 * (xr + 1);

  for (int t = 0; t < ntiles; ++t) {
    const int kt0 = t * 64;
    const char* cK = (t & 1) ? sK1 : sK0;
    const char* cV = (t & 1) ? sV1 : sV0;
    if (t + 1 < ntiles) {
      stageK(t + 1);
      loadV(t + 1, vr);
    }

    f32x4 sacc[4] = {};
#pragma unroll
    for (int kk = 0; kk < 4; ++kk) {
      int kb = (lane >> 4) * 16 + kk * 64;
#pragma unroll
      for (int ni = 0; ni < 4; ++ni) {
        int krow = ni * 16 + (lane & 15);
        bf16x8 bk =
            *(const bf16x8*)(cK + ((krow * 256 + kb) ^ ((krow & 15) << 4)));
        sacc[ni] = __builtin_amdgcn_mfma_f32_16x16x32_bf16(aq[kk], bk,
                                                           sacc[ni], 0, 0, 0);
      }
    }

    const float scale = 0.08838834764831845f;
#pragma unroll
    for (int r = 0; r < 4; ++r) {
      int qg = qb0 + wv * 16 + rbase + r;
      float mx = -1e30f;
#pragma unroll
      for (int ni = 0; ni < 4; ++ni) {
        int cg = kt0 + ni * 16 + cbase;
        float sv = sacc[ni][r] * scale;
        sv = (cg <= qg) ? sv : -1e30f;
        sacc[ni][r] = sv;
        mx = fmaxf(mx, sv);
      }
      mx = fmaxf(mx, __shfl_xor(mx, 1));
      mx = fmaxf(mx, __shfl_xor(mx, 2));
      mx = fmaxf(mx, __shfl_xor(mx, 4));
      mx = fmaxf(mx, __shfl_xor(mx, 8));
      float mnew = fmaxf(m_r[r], mx);
      float sf = __expf(m_r[r] - mnew);
      m_r[r] = mnew;
      float rsum = 0.f;
#pragma unroll
      for (int ni = 0; ni < 4; ++ni) {
        float pv = __expf(sacc[ni][r] - mnew);
        sacc[ni][r] = pv;
        rsum += pv;
      }
      rsum += __shfl_xor(rsum, 1);
      rsum += __shfl_xor(rsum, 2);
      rsum += __shfl_xor(rsum, 4);
      rsum += __shfl_xor(rsum, 8);
      l_r[r] = l_r[r] * sf + rsum;
#pragma unroll
      for (int nt2 = 0; nt2 < 8; ++nt2) oacc[nt2][r] *= sf;
    }

    char* pw = sP + wv * 2048;
#pragma unroll
    for (int ni = 0; ni < 4; ++ni)
#pragma unroll
      for (int r = 0; r < 4; ++r) {
        int row = rbase + r;
        int cb2 = (ni * 16 + cbase) * 2;
        *(unsigned short*)(pw + ((row * 128 + cb2) ^ ((row & 7) << 4))) =
            f2bf(sacc[ni][r]);
      }
    asm volatile("s_waitcnt lgkmcnt(0)" ::: "memory");

#pragma unroll
    for (int kk = 0; kk < 2; ++kk) {
      int kb = (lane >> 4) * 16 + kk * 64;
      int prow = lane & 15;
      bf16x8 ap =
          *(const bf16x8*)(pw + ((prow * 128 + kb) ^ ((prow & 7) << 4)));
#pragma unroll
      for (int nt2 = 0; nt2 < 8; ++nt2) {
        int vrow = nt2 * 16 + (lane & 15);
        bf16x8 bv =
            *(const bf16x8*)(cV + ((vrow * 128 + kb) ^ ((vrow & 7) << 4)));
        oacc[nt2] =
            __builtin_amdgcn_mfma_f32_16x16x32_bf16(ap, bv, oacc[nt2], 0, 0, 0);
      }
    }

    if (t + 1 < ntiles) {
      asm volatile("s_waitcnt vmcnt(0)" ::: "memory");
      writeV(t + 1, vr);
    }
    __syncthreads();
  }

#pragma unroll
  for (int nt2 = 0; nt2 < 8; ++nt2)
#pragma unroll
    for (int r = 0; r < 4; ++r) {
      size_t row = (size_t)(qb0 + wv * 16 + rbase + r);
      int col = nt2 * 16 + cbase;
      Ob[row * (NH * DH) + h * DH + col] = f2bf(oacc[nt2][r] / l_r[r]);
    }
}

// ---------------------------------------------------------------- host
extern "C" void kernel_launch(void* const* d_in, const int* in_sizes, int n_in,
                              void* d_out, int out_size, void* d_ws,
                              size_t ws_size, hipStream_t stream) {
  const float* hs  = (const float*)d_in[0];
  const float* wq  = (const float*)d_in[1];
  const float* wk  = (const float*)d_in[2];
  const float* wvp = (const float*)d_in[3];
  const float* wo  = (const float*)d_in[4];
  const float* wg  = (const float*)d_in[5];
  const float* wu  = (const float*)d_in[6];
  const float* wd  = (const float*)d_in[7];
  const float* ln1 = (const float*)d_in[8];
  const float* ln2 = (const float*)d_in[9];

  char* p = (char*)d_ws;
  size_t need = 0;
  auto alloc = [&](size_t bytes) {
    char* r = p + need;
    need += (bytes + 255) & ~(size_t)255;
    return r;
  };
  unsigned short* T1   = (unsigned short*)alloc((size_t)FF * HID * 2);
  unsigned short* xn   = (unsigned short*)alloc((size_t)SEQ * HID * 2);
  unsigned short* qkv  = (unsigned short*)alloc((size_t)SEQ * QKVN * 2);
  unsigned short* ab   = (unsigned short*)alloc((size_t)SEQ * NH * DH * 2);
  float*          h2   = (float*)alloc((size_t)SEQ * HID * 4);
  unsigned short* xn2  = (unsigned short*)alloc((size_t)SEQ * HID * 2);
  unsigned short* gbuf = (unsigned short*)alloc((size_t)SEQ * FF * 2);
  unsigned short* ubuf = (unsigned short*)alloc((size_t)SEQ * FF * 2);
  size_t need_base = need;
  unsigned short* T2   = (unsigned short*)alloc((size_t)FF * HID * 2);
  const bool fat = (ws_size >= need);
  if (ws_size < need_base) return;  // workspace too small: fail visibly

  // o-proj partials: gbuf (33.5MB of 58.7) and the dead xn+qkv region.
  float* pO0 = (float*)gbuf;
  float* pO1 = (float*)xn;
  // down-proj partials: fat -> T2 (wu dead by then); else ubuf + xn region.
  float* pD0 = fat ? (float*)T2 : (float*)ubuf;
  float* pD1 = fat ? (float*)(T2 + (size_t)SEQ * HID * 2) : (float*)xn;
  (void)ubuf;

  // 1) rmsnorm1
  rmsnorm_kernel<<<SEQ, 256, 0, stream>>>(hs, ln1, xn);
  // 2) transpose wq|wk|wv into T1 -> [QKVN][HID] bf16
  wtrans_kernel<<<dim3(HID / 64, HID / 64), 256, 0, stream>>>(wq, T1, HID, HID);
  wtrans_kernel<<<dim3(HID / 64, (NKV * DH) / 64), 256, 0, stream>>>(
      wk, T1 + (size_t)(NH * DH) * HID, HID, NKV * DH);
  wtrans_kernel<<<dim3(HID / 64, (NKV * DH) / 64), 256, 0, stream>>>(
      wvp, T1 + (size_t)(NH * DH + NKV * DH) * HID, HID, NKV * DH);
  // 3) fused qkv projection; fat: + wo-transpose prelude (64 blocks)
  if (fat) {
    gemm8p_kernel<0><<<64 + 192, 512, 0, stream>>>(
        xn, T1, qkv, nullptr, SEQ / 256, QKVN, HID, 1, wo, T2, HID, HID, 64);
  } else {
    gemm8p_kernel<0><<<192, 512, 0, stream>>>(
        xn, T1, qkv, nullptr, SEQ / 256, QKVN, HID, 1, nullptr, nullptr, 64, 64, 0);
  }
  // 4) RoPE
  rope_kernel<<<(SEQ * NH * 64) / 256, 256, 0, stream>>>(qkv, NH, QKVN);
  rope_kernel<<<(SEQ * NKV * 64) / 256, 256, 0, stream>>>(qkv + NH * DH, NKV,
                                                          QKVN);
  // 5) attention
  attn_kernel<<<512, 512, 0, stream>>>(qkv, ab);
  // 6) o-proj split-K=2 + fused combine+rmsnorm2 -> h2, xn2
  unsigned short* Wo = fat ? T2 : T1;
  if (!fat)
    wtrans_kernel<<<dim3(HID / 64, HID / 64), 256, 0, stream>>>(wo, T1, HID, HID);
  gemm8p_kernel<2><<<256, 512, 0, stream>>>(
      ab, Wo, pO0, pO1, SEQ / 256, HID, HID, 2, nullptr, nullptr, 64, 64, 0);
  combine_rms_kernel<<<SEQ, 256, 0, stream>>>(pO0, pO1, hs, ln2, h2, xn2);
  // 7) gate; fat: + wu-transpose prelude (1024 blocks first)
  wtrans_kernel<<<dim3(HID / 64, FF / 64), 256, 0, stream>>>(wg, T1, HID, FF);
  if (fat) {
    gemm8p_kernel<0><<<1024 + 448, 512, 0, stream>>>(
        xn2, T1, gbuf, nullptr, SEQ / 256, FF, HID, 1, wu, T2, HID, FF, 1024);
  } else {
    gemm8p_kernel<0><<<448, 512, 0, stream>>>(
        xn2, T1, gbuf, nullptr, SEQ / 256, FF, HID, 1, nullptr, nullptr, 64, 64, 0);
  }
  // 8) up with fused SiLU epilogue; fat: + wd-transpose prelude into T1
  if (fat) {
    gemm8p_kernel<3><<<1024 + 448, 512, 0, stream>>>(
        xn2, T2, gbuf, gbuf, SEQ / 256, FF, HID, 1, wd, T1, FF, HID, 1024);
  } else {
    wtrans_kernel<<<dim3(HID / 64, FF / 64), 256, 0, stream>>>(wu, T1, HID, FF);
    gemm8p_kernel<3><<<448, 512, 0, stream>>>(
        xn2, T1, gbuf, gbuf, SEQ / 256, FF, HID, 1, nullptr, nullptr, 64, 64, 0);
  }
  // 9) down-proj split-K=2 + combine with residual h2 -> out
  if (!fat)
    wtrans_kernel<<<dim3(FF / 64, HID / 64), 256, 0, stream>>>(wd, T1, FF, HID);
  gemm8p_kernel<2><<<256, 512, 0, stream>>>(
      gbuf, T1, pD0, pD1, SEQ / 256, HID, FF, 2, nullptr, nullptr, 64, 64, 0);
  combine_kernel<<<(SEQ * HID) / 1024, 256, 0, stream>>>(pD0, pD1, h2,
                                                         (float*)d_out);
}

// Round 11
// 1224.205 us; speedup vs baseline: 72.9680x; 1.0590x over previous
//
#include <hip/hip_runtime.h>

typedef short bf16x8 __attribute__((ext_vector_type(8)));
typedef float f32x4 __attribute__((ext_vector_type(4)));

#define DEV __device__ __forceinline__

constexpr int SEQ = 2048;
constexpr int HID = 4096;
constexpr int NH  = 32;
constexpr int NKV = 8;
constexpr int DH  = 128;
constexpr int FF  = 14336;
constexpr int QKVN = NH * DH + 2 * NKV * DH;  // 6144

DEV unsigned short f2bf(float f) {
  union { float f; unsigned u; } x; x.f = f;
  unsigned r = x.u + 0x7fffu + ((x.u >> 16) & 1u);
  return (unsigned short)(r >> 16);
}
DEV float bf2f(unsigned short u) {
  union { unsigned u; float f; } x; x.u = ((unsigned)u) << 16; return x.f;
}
DEV void gload16(const void* g, void* l) {
  __builtin_amdgcn_global_load_lds(
      (const __attribute__((address_space(1))) unsigned*)g,
      (__attribute__((address_space(3))) unsigned*)l, 16, 0, 0);
}

// Shared grid-stride transpose body (64x64 fp32 tile -> bf16 transposed),
// 2 teams of 256 threads per block. Used by the fat tails.
DEV void wtrans_tail(char* smbase, int tid, int tile0, int stride,
                     const float* __restrict__ TW,
                     unsigned short* __restrict__ TWT, int TK, int TN) {
  const int team = tid >> 8, lt = tid & 255;
  unsigned short(*tt)[72] = (unsigned short(*)[72])(smbase + team * 9216);
  const int tilesK = TK >> 6;
  const int tot = tilesK * (TN >> 6);
  const int tk = lt >> 4;
  const int tn4 = (lt & 15) * 4;
  for (int tile = tile0 * 2 + team; tile < tot; tile += stride * 2) {
    const int k0 = (tile % tilesK) << 6;
    const int n0t = (tile / tilesK) << 6;
#pragma unroll
    for (int p = 0; p < 4; ++p) {
      int k = tk + p * 16;
      float4 v = *(const float4*)(TW + (size_t)(k0 + k) * TN + n0t + tn4);
      tt[tn4 + 0][k] = f2bf(v.x);
      tt[tn4 + 1][k] = f2bf(v.y);
      tt[tn4 + 2][k] = f2bf(v.z);
      tt[tn4 + 3][k] = f2bf(v.w);
    }
    __syncthreads();
#pragma unroll
    for (int p = 0; p < 4; ++p) {
      int n = tk + p * 16;
      ushort4 o = *(const ushort4*)&tt[n][tn4];
      *(ushort4*)(TWT + (size_t)(n0t + n) * TK + k0 + tn4) = o;
    }
    __syncthreads();
  }
}

// ---------------------------------------------------------------- RMSNorm
__global__ __launch_bounds__(256) void rmsnorm_kernel(
    const float* __restrict__ x, const float* __restrict__ w,
    unsigned short* __restrict__ out) {
  const int row = blockIdx.x;
  const int tid = threadIdx.x;
  const float* xr = x + (size_t)row * HID;
  float4 v[4];
  float ss = 0.f;
#pragma unroll
  for (int i = 0; i < 4; ++i) {
    v[i] = *(const float4*)(xr + i * 1024 + tid * 4);
    ss += v[i].x * v[i].x + v[i].y * v[i].y + v[i].z * v[i].z + v[i].w * v[i].w;
  }
#pragma unroll
  for (int m = 1; m < 64; m <<= 1) ss += __shfl_xor(ss, m);
  __shared__ float red[4];
  if ((tid & 63) == 0) red[tid >> 6] = ss;
  __syncthreads();
  float tot = red[0] + red[1] + red[2] + red[3];
  float rms = rsqrtf(tot / (float)HID + 1e-5f);
  unsigned short* orow = out + (size_t)row * HID;
#pragma unroll
  for (int i = 0; i < 4; ++i) {
    int base = i * 1024 + tid * 4;
    ushort4 o;
    o.x = f2bf(v[i].x * rms * w[base + 0]);
    o.y = f2bf(v[i].y * rms * w[base + 1]);
    o.z = f2bf(v[i].z * rms * w[base + 2]);
    o.w = f2bf(v[i].w * rms * w[base + 3]);
    *(ushort4*)(orow + base) = o;
  }
}

// ------------------------------------------------- weight transpose+convert
__global__ __launch_bounds__(256) void wtrans_kernel(
    const float* __restrict__ W, unsigned short* __restrict__ WT, int K,
    int N) {
  __shared__ unsigned short t[64][72];
  const int k0 = blockIdx.x * 64, n0 = blockIdx.y * 64;
  const int tid = threadIdx.x;
  const int tk = tid >> 4;
  const int tn4 = (tid & 15) * 4;
#pragma unroll
  for (int p = 0; p < 4; ++p) {
    int k = tk + p * 16;
    float4 v = *(const float4*)(W + (size_t)(k0 + k) * N + n0 + tn4);
    t[tn4 + 0][k] = f2bf(v.x);
    t[tn4 + 1][k] = f2bf(v.y);
    t[tn4 + 2][k] = f2bf(v.z);
    t[tn4 + 3][k] = f2bf(v.w);
  }
  __syncthreads();
#pragma unroll
  for (int p = 0; p < 4; ++p) {
    int n = tk + p * 16;
    ushort4 o = *(const ushort4*)&t[n][tn4];
    *(ushort4*)(WT + (size_t)(n0 + n) * K + k0 + tn4) = o;
  }
}

// ---------------------------------------------------------------- RoPE (in-place, strided)
// Covers nheads contiguous 128-wide head slots starting at col 0 of x.
__global__ __launch_bounds__(256) void rope_kernel(unsigned short* __restrict__ x,
                                                   int nheads, int ld) {
  const int gid = blockIdx.x * 256 + threadIdx.x;
  const int i = gid & 63;
  const int t = gid >> 6;
  const int s = t / nheads;
  const int hh = t - s * nheads;
  float ang = (float)s * exp2f((float)i * (-29.897352853986263f / 64.f));
  float sn, cs;
  sincosf(ang, &sn, &cs);
  size_t base = (size_t)s * ld + hh * DH + i;
  float x1 = bf2f(x[base]);
  float x2 = bf2f(x[base + 64]);
  x[base]      = f2bf(x1 * cs - x2 * sn);
  x[base + 64] = f2bf(x2 * cs + x1 * sn);
}

// ---------------------------------------------------------------- combine (final)
__global__ __launch_bounds__(256) void combine_kernel(
    const float* __restrict__ p0, const float* __restrict__ p1,
    const float* __restrict__ res, float* __restrict__ out) {
  const size_t i = ((size_t)blockIdx.x * 256 + threadIdx.x) * 4;
  float4 a = *(const float4*)(p0 + i);
  float4 b = *(const float4*)(p1 + i);
  float4 c = *(const float4*)(res + i);
  float4 o;
  o.x = a.x + b.x + c.x;
  o.y = a.y + b.y + c.y;
  o.z = a.z + b.z + c.z;
  o.w = a.w + b.w + c.w;
  *(float4*)(out + i) = o;
}

// ---------------------------------------------------------------- combine + rmsnorm
__global__ __launch_bounds__(256) void combine_rms_kernel(
    const float* __restrict__ p0, const float* __restrict__ p1,
    const float* __restrict__ res, const float* __restrict__ w,
    float* __restrict__ h2, unsigned short* __restrict__ xn2) {
  const int row = blockIdx.x;
  const int tid = threadIdx.x;
  const size_t base = (size_t)row * HID;
  float4 h[4];
  float ss = 0.f;
#pragma unroll
  for (int i = 0; i < 4; ++i) {
    size_t idx = base + i * 1024 + tid * 4;
    float4 a = *(const float4*)(p0 + idx);
    float4 b = *(const float4*)(p1 + idx);
    float4 c = *(const float4*)(res + idx);
    h[i].x = a.x + b.x + c.x;
    h[i].y = a.y + b.y + c.y;
    h[i].z = a.z + b.z + c.z;
    h[i].w = a.w + b.w + c.w;
    *(float4*)(h2 + idx) = h[i];
    ss += h[i].x * h[i].x + h[i].y * h[i].y + h[i].z * h[i].z + h[i].w * h[i].w;
  }
#pragma unroll
  for (int m = 1; m < 64; m <<= 1) ss += __shfl_xor(ss, m);
  __shared__ float red[4];
  if ((tid & 63) == 0) red[tid >> 6] = ss;
  __syncthreads();
  float tot = red[0] + red[1] + red[2] + red[3];
  float rms = rsqrtf(tot / (float)HID + 1e-5f);
#pragma unroll
  for (int i = 0; i < 4; ++i) {
    int off = i * 1024 + tid * 4;
    ushort4 o;
    o.x = f2bf(h[i].x * rms * w[off + 0]);
    o.y = f2bf(h[i].y * rms * w[off + 1]);
    o.z = f2bf(h[i].z * rms * w[off + 2]);
    o.w = f2bf(h[i].w * rms * w[off + 3]);
    *(ushort4*)(xn2 + base + off) = o;
  }
}

// ---------------------------------------------------------------- GEMM 8-phase (fat, tail transposes)
// C[M,N] = A[M,Kld](bf16,row) @ BT[N,Kld](bf16,row)^T, optional split-K.
// Tile 256x256; BK=64; 512 threads = 8 waves (2M x 4N).
// Fat co-schedule: blocks with blockIdx >= gridDim-n_t run a grid-stride
// weight transpose (rides the GEMM's ragged finish as a tail).
// EPI=0: bf16 -> Cv0.  EPI=2: fp32 partial -> (s?Cv1:Cv0).
// EPI=3: bf16 silu(g)*acc -> Cv0, g read from Cv1 (bf16).
template <int EPI>
__global__ __launch_bounds__(512, 2) void gemm8p_kernel(
    const unsigned short* __restrict__ A, const unsigned short* __restrict__ BT,
    void* __restrict__ Cv0, void* __restrict__ Cv1, int gridM, int N, int Kld,
    int nsplit, const float* __restrict__ TW, unsigned short* __restrict__ TWT,
    int TK, int TN, int n_t) {
  constexpr int MF = 4;
  constexpr int ABYTES = 256 * 128;  // 32KB
  constexpr int BUFBYTES = ABYTES + 32768;
  __shared__ __align__(128) char sm[2 * BUFBYTES];

  const int tid = threadIdx.x;
  const int nwg = gridDim.x - n_t;

  if ((int)blockIdx.x >= nwg) {
    wtrans_tail(sm, tid, (int)blockIdx.x - nwg, n_t, TW, TWT, TK, TN);
    return;
  }

  // ---------------- GEMM path
  const int lane = tid & 63;
  const int wv   = tid >> 6;
  const int b = blockIdx.x;
  const int logical = (b & 7) * (nwg >> 3) + (b >> 3);
  const int ntiles = nwg / nsplit;
  const int s = logical / ntiles;
  const int r = logical - s * ntiles;
  const int m0 = (r % gridM) * 256;
  const int n0 = (r / gridM) * 256;
  const int Klen = Kld / nsplit;
  const int koff = s * Klen;
  const int wm = (wv >> 2) * 128;
  const int wn = (wv & 3) * 64;
  const int nt = Klen >> 6;

  const int srow = tid >> 3;
  const int scolb = (tid & 7) * 16;
  const int sldsbase = wv * 1024;  // HW adds lane*16

  auto stage = [&](int h, int t) {
    const int buf = t & 1;
    const int kt = koff + t * 64;
    char* ldsOp;
    const unsigned short* g;
    int grow0, rowBase;
    if (h < 2) {
      ldsOp = sm + buf * BUFBYTES + ABYTES; g = BT; grow0 = n0; rowBase = h * 128;
    } else {
      ldsOp = sm + buf * BUFBYTES;          g = A;  grow0 = m0; rowBase = (h - 2) * 128;
    }
#pragma unroll
    for (int rr = 0; rr < 2; ++rr) {
      int row = rowBase + rr * 64 + srow;
      const char* gp = (const char*)g + ((size_t)(grow0 + row) * Kld + kt) * 2 +
                       (scolb ^ ((row & 7) << 4));
      gload16(gp, ldsOp + rowBase * 128 + rr * 8192 + sldsbase);
    }
  };

  const int kb0 = (lane >> 4) * 16;
  const int lrow = lane & 15;
  auto ldA = [&](const char* sA, int mh, int mf, int ks) {
    int row = wm + mh * 64 + mf * 16 + lrow;
    return *(const bf16x8*)(sA + ((row * 128 + kb0 + ks * 64) ^ ((row & 7) << 4)));
  };
  auto ldB = [&](const char* sB, int j, int ks) {
    int col = wn + j * 16 + lrow;
    return *(const bf16x8*)(sB + ((col * 128 + kb0 + ks * 64) ^ ((col & 7) << 4)));
  };

  f32x4 acc[2 * MF][4] = {};

  stage(2, 0); stage(3, 0); stage(0, 0); stage(1, 0);
  if (nt > 1) {
    stage(0, 1); stage(1, 1);
    asm volatile("s_waitcnt vmcnt(4)" ::: "memory");
  } else {
    asm volatile("s_waitcnt vmcnt(0)" ::: "memory");
  }
  __builtin_amdgcn_s_barrier();

  for (int t = 0; t < nt; ++t) {
    const char* sA = sm + (t & 1) * BUFBYTES;
    const char* sB = sA + ABYTES;
    bf16x8 a[MF], bb[4][2];

#pragma unroll
    for (int j = 0; j < 4; ++j) bb[j][0] = ldB(sB, j, 0);
#pragma unroll
    for (int mf = 0; mf < MF; ++mf) a[mf] = ldA(sA, 0, mf, 0);
    if (t + 1 < nt) stage(2, t + 1);
    __builtin_amdgcn_sched_barrier(0);
    __builtin_amdgcn_s_barrier();
    __builtin_amdgcn_s_setprio(1);
#pragma unroll
    for (int mf = 0; mf < MF; ++mf)
#pragma unroll
      for (int j = 0; j < 4; ++j)
        acc[mf][j] = __builtin_amdgcn_mfma_f32_16x16x32_bf16(
            a[mf], bb[j][0], acc[mf][j], 0, 0, 0);
    __builtin_amdgcn_s_setprio(0);
    __builtin_amdgcn_sched_barrier(0);
    __builtin_amdgcn_s_barrier();

#pragma unroll
    for (int j = 0; j < 4; ++j) bb[j][1] = ldB(sB, j, 1);
#pragma unroll
    for (int mf = 0; mf < MF; ++mf) a[mf] = ldA(sA, 0, mf, 1);
    if (t + 1 < nt) stage(3, t + 1);
    __builtin_amdgcn_sched_barrier(0);
    __builtin_amdgcn_s_barrier();
    __builtin_amdgcn_s_setprio(1);
#pragma unroll
    for (int mf = 0; mf < MF; ++mf)
#pragma unroll
      for (int j = 0; j < 4; ++j)
        acc[mf][j] = __builtin_amdgcn_mfma_f32_16x16x32_bf16(
            a[mf], bb[j][1], acc[mf][j], 0, 0, 0);
    __builtin_amdgcn_s_setprio(0);
    __builtin_amdgcn_sched_barrier(0);
    __builtin_amdgcn_s_barrier();

#pragma unroll
    for (int mf = 0; mf < MF; ++mf) a[mf] = ldA(sA, 1, mf, 0);
    if (t + 2 < nt) stage(0, t + 2);
    __builtin_amdgcn_sched_barrier(0);
    __builtin_amdgcn_s_barrier();
    __builtin_amdgcn_s_setprio(1);
#pragma unroll
    for (int mf = 0; mf < MF; ++mf)
#pragma unroll
      for (int j = 0; j < 4; ++j)
        acc[MF + mf][j] = __builtin_amdgcn_mfma_f32_16x16x32_bf16(
            a[mf], bb[j][0], acc[MF + mf][j], 0, 0, 0);
    __builtin_amdgcn_s_setprio(0);
    __builtin_amdgcn_sched_barrier(0);
    __builtin_amdgcn_s_barrier();

#pragma unroll
    for (int mf = 0; mf < MF; ++mf) a[mf] = ldA(sA, 1, mf, 1);
    if (t + 2 < nt) {
      stage(1, t + 2);
      asm volatile("s_waitcnt vmcnt(4)" ::: "memory");
    } else {
      asm volatile("s_waitcnt vmcnt(0)" ::: "memory");
    }
    __builtin_amdgcn_sched_barrier(0);
    __builtin_amdgcn_s_barrier();
    __builtin_amdgcn_s_setprio(1);
#pragma unroll
    for (int mf = 0; mf < MF; ++mf)
#pragma unroll
      for (int j = 0; j < 4; ++j)
        acc[MF + mf][j] = __builtin_amdgcn_mfma_f32_16x16x32_bf16(
            a[mf], bb[j][1], acc[MF + mf][j], 0, 0, 0);
    __builtin_amdgcn_s_setprio(0);
    __builtin_amdgcn_sched_barrier(0);
    __builtin_amdgcn_s_barrier();
  }

  const int rb = (lane >> 4) * 4;
  float* P = (float*)(s ? Cv1 : Cv0);
#pragma unroll
  for (int i = 0; i < 2 * MF; ++i) {
    const int mh = i / MF, mf = i % MF;
#pragma unroll
    for (int j = 0; j < 4; ++j) {
#pragma unroll
      for (int rr = 0; rr < 4; ++rr) {
        size_t row = (size_t)(m0 + wm + mh * 64 + mf * 16 + rb + rr);
        size_t col = (size_t)(n0 + wn + j * 16 + lrow);
        float vv = acc[i][j][rr];
        if (EPI == 0) {
          ((unsigned short*)Cv0)[row * N + col] = f2bf(vv);
        } else if (EPI == 2) {
          P[row * N + col] = vv;
        } else {  // EPI == 3: silu(g) * acc
          float g = bf2f(((const unsigned short*)Cv1)[row * N + col]);
          float sl = g / (1.f + __expf(-g));
          ((unsigned short*)Cv0)[row * N + col] = f2bf(sl * vv);
        }
      }
    }
  }
}

// ---------------------------------------------------------------- Flash attention (fat)
// attn blocks [0, grid-n_t): 128 q-rows x 1 head, 8 waves, LPT order.
// Tail blocks [grid-n_t, grid): grid-stride wg-transpose (backfills the
// ragged short-block round; attn is latency-bound at 2.5% HBM).
__global__ __launch_bounds__(512, 1) void attn_kernel(
    const unsigned short* __restrict__ QKV, unsigned short* __restrict__ Ob,
    const float* __restrict__ TW, unsigned short* __restrict__ TWT, int TK,
    int TN, int n_t) {
  __shared__ __align__(128) char sm[114688];
  const int tid  = threadIdx.x;
  const int nattn = gridDim.x - n_t;
  if ((int)blockIdx.x >= nattn) {
    wtrans_tail(sm, tid, (int)blockIdx.x - nattn, n_t, TW, TWT, TK, TN);
    return;
  }
  char* sQ  = sm;
  char* sK0 = sm + 32768;
  char* sK1 = sm + 49152;
  char* sV0 = sm + 65536;
  char* sV1 = sm + 81920;
  char* sP  = sm + 98304;
  const int lane = tid & 63;
  const int wv   = tid >> 6;
  const int logical = blockIdx.x;
  const int xr = 15 - (logical >> 5);
  const int h = logical & 31;
  const int qb0 = xr * 128;
  const int hkv = h >> 2;
  const int rbase = (lane >> 4) * 4;
  const int cbase = lane & 15;
  const unsigned short* Qp = QKV + h * DH;
  const unsigned short* Kp = QKV + NH * DH + hkv * DH;
  const unsigned short* Vp = QKV + NH * DH + NKV * DH + hkv * DH;

#pragma unroll
  for (int i = 0; i < 4; ++i) {
    int offs = i * 8192 + tid * 16;
    int row = offs >> 8, col = offs & 255;
    const char* gp = (const char*)Qp + ((size_t)(qb0 + row) * QKVN) * 2 +
                     (col ^ ((row & 15) << 4));
    gload16(gp, sQ + i * 8192 + wv * 1024);
  }

  auto stageK = [&](int t) {
    char* dst = (t & 1) ? sK1 : sK0;
    const int kt0 = t * 64;
#pragma unroll
    for (int i = 0; i < 2; ++i) {
      int offs = i * 8192 + tid * 16;
      int row = offs >> 8, col = offs & 255;
      const char* gp = (const char*)Kp + ((size_t)(kt0 + row) * QKVN) * 2 +
                       (col ^ ((row & 15) << 4));
      gload16(gp, dst + i * 8192 + wv * 1024);
    }
  };

  const int d4  = (tid & 31) * 4;
  const int kv4 = (tid >> 5) * 4;
  const int rot = (tid >> 1) & 3;
  auto loadV = [&](int t, ushort4* vr) {
    const unsigned short* g0 = Vp + (size_t)(t * 64 + kv4) * QKVN + d4;
#pragma unroll
    for (int k = 0; k < 4; ++k) vr[k] = *(const ushort4*)(g0 + (size_t)k * QKVN);
  };
  auto writeV = [&](int t, const ushort4* vr) {
    char* dst = (t & 1) ? sV1 : sV0;
    const unsigned short* a0 = (const unsigned short*)&vr[0];
    const unsigned short* a1 = (const unsigned short*)&vr[1];
    const unsigned short* a2 = (const unsigned short*)&vr[2];
    const unsigned short* a3 = (const unsigned short*)&vr[3];
#pragma unroll
    for (int j = 0; j < 4; ++j) {
      int jj = (j + rot) & 3;
      int dd = d4 + jj;
      uint2 pk;
      pk.x = (unsigned)a0[jj] | ((unsigned)a1[jj] << 16);
      pk.y = (unsigned)a2[jj] | ((unsigned)a3[jj] << 16);
      *(uint2*)(dst + ((dd * 128 + kv4 * 2) ^ ((dd & 7) << 4))) = pk;
    }
  };

  ushort4 vr[4];
  stageK(0);
  loadV(0, vr);
  asm volatile("s_waitcnt vmcnt(0)" ::: "memory");
  writeV(0, vr);
  __syncthreads();

  const int qrow = wv * 16 + (lane & 15);
  bf16x8 aq[4];
#pragma unroll
  for (int kk = 0; kk < 4; ++kk) {
    int kb = (lane >> 4) * 16 + kk * 64;
    aq[kk] = *(const bf16x8*)(sQ + ((qrow * 256 + kb) ^ ((qrow & 15) << 4)));
  }

  f32x4 oacc[8] = {};
  float m_r[4] = {-1e30f, -1e30f, -1e30f, -1e30f};
  float l_r[4] = {0.f, 0.f, 0.f, 0.f};
  const int ntiles = 2 * (xr + 1);

  for (int t = 0; t < ntiles; ++t) {
    const int kt0 = t * 64;
    const char* cK = (t & 1) ? sK1 : sK0;
    const char* cV = (t & 1) ? sV1 : sV0;
    if (t + 1 < ntiles) {
      stageK(t + 1);
      loadV(t + 1, vr);
    }

    f32x4 sacc[4] = {};
#pragma unroll
    for (int kk = 0; kk < 4; ++kk) {
      int kb = (lane >> 4) * 16 + kk * 64;
#pragma unroll
      for (int ni = 0; ni < 4; ++ni) {
        int krow = ni * 16 + (lane & 15);
        bf16x8 bk =
            *(const bf16x8*)(cK + ((krow * 256 + kb) ^ ((krow & 15) << 4)));
        sacc[ni] = __builtin_amdgcn_mfma_f32_16x16x32_bf16(aq[kk], bk,
                                                           sacc[ni], 0, 0, 0);
      }
    }

    const float scale = 0.08838834764831845f;
#pragma unroll
    for (int r = 0; r < 4; ++r) {
      int qg = qb0 + wv * 16 + rbase + r;
      float mx = -1e30f;
#pragma unroll
      for (int ni = 0; ni < 4; ++ni) {
        int cg = kt0 + ni * 16 + cbase;
        float sv = sacc[ni][r] * scale;
        sv = (cg <= qg) ? sv : -1e30f;
        sacc[ni][r] = sv;
        mx = fmaxf(mx, sv);
      }
      mx = fmaxf(mx, __shfl_xor(mx, 1));
      mx = fmaxf(mx, __shfl_xor(mx, 2));
      mx = fmaxf(mx, __shfl_xor(mx, 4));
      mx = fmaxf(mx, __shfl_xor(mx, 8));
      float mnew = fmaxf(m_r[r], mx);
      float sf = __expf(m_r[r] - mnew);
      m_r[r] = mnew;
      float rsum = 0.f;
#pragma unroll
      for (int ni = 0; ni < 4; ++ni) {
        float pv = __expf(sacc[ni][r] - mnew);
        sacc[ni][r] = pv;
        rsum += pv;
      }
      rsum += __shfl_xor(rsum, 1);
      rsum += __shfl_xor(rsum, 2);
      rsum += __shfl_xor(rsum, 4);
      rsum += __shfl_xor(rsum, 8);
      l_r[r] = l_r[r] * sf + rsum;
#pragma unroll
      for (int nt2 = 0; nt2 < 8; ++nt2) oacc[nt2][r] *= sf;
    }

    char* pw = sP + wv * 2048;
#pragma unroll
    for (int ni = 0; ni < 4; ++ni)
#pragma unroll
      for (int r = 0; r < 4; ++r) {
        int row = rbase + r;
        int cb2 = (ni * 16 + cbase) * 2;
        *(unsigned short*)(pw + ((row * 128 + cb2) ^ ((row & 7) << 4))) =
            f2bf(sacc[ni][r]);
      }
    asm volatile("s_waitcnt lgkmcnt(0)" ::: "memory");

#pragma unroll
    for (int kk = 0; kk < 2; ++kk) {
      int kb = (lane >> 4) * 16 + kk * 64;
      int prow = lane & 15;
      bf16x8 ap =
          *(const bf16x8*)(pw + ((prow * 128 + kb) ^ ((prow & 7) << 4)));
#pragma unroll
      for (int nt2 = 0; nt2 < 8; ++nt2) {
        int vrow = nt2 * 16 + (lane & 15);
        bf16x8 bv =
            *(const bf16x8*)(cV + ((vrow * 128 + kb) ^ ((vrow & 7) << 4)));
        oacc[nt2] =
            __builtin_amdgcn_mfma_f32_16x16x32_bf16(ap, bv, oacc[nt2], 0, 0, 0);
      }
    }

    if (t + 1 < ntiles) {
      asm volatile("s_waitcnt vmcnt(0)" ::: "memory");
      writeV(t + 1, vr);
    }
    __syncthreads();
  }

#pragma unroll
  for (int nt2 = 0; nt2 < 8; ++nt2)
#pragma unroll
    for (int r = 0; r < 4; ++r) {
      size_t row = (size_t)(qb0 + wv * 16 + rbase + r);
      int col = nt2 * 16 + cbase;
      Ob[row * (NH * DH) + h * DH + col] = f2bf(oacc[nt2][r] / l_r[r]);
    }
}

// ---------------------------------------------------------------- host
extern "C" void kernel_launch(void* const* d_in, const int* in_sizes, int n_in,
                              void* d_out, int out_size, void* d_ws,
                              size_t ws_size, hipStream_t stream) {
  const float* hs  = (const float*)d_in[0];
  const float* wq  = (const float*)d_in[1];
  const float* wk  = (const float*)d_in[2];
  const float* wvp = (const float*)d_in[3];
  const float* wo  = (const float*)d_in[4];
  const float* wg  = (const float*)d_in[5];
  const float* wu  = (const float*)d_in[6];
  const float* wd  = (const float*)d_in[7];
  const float* ln1 = (const float*)d_in[8];
  const float* ln2 = (const float*)d_in[9];

  char* p = (char*)d_ws;
  size_t need = 0;
  auto alloc = [&](size_t bytes) {
    char* r = p + need;
    need += (bytes + 255) & ~(size_t)255;
    return r;
  };
  unsigned short* T1   = (unsigned short*)alloc((size_t)FF * HID * 2);
  unsigned short* xn   = (unsigned short*)alloc((size_t)SEQ * HID * 2);
  unsigned short* qkv  = (unsigned short*)alloc((size_t)SEQ * QKVN * 2);
  unsigned short* ab   = (unsigned short*)alloc((size_t)SEQ * NH * DH * 2);
  float*          h2   = (float*)alloc((size_t)SEQ * HID * 4);
  unsigned short* xn2  = (unsigned short*)alloc((size_t)SEQ * HID * 2);
  unsigned short* gbuf = (unsigned short*)alloc((size_t)SEQ * FF * 2);
  unsigned short* ubuf = (unsigned short*)alloc((size_t)SEQ * FF * 2);
  size_t need_base = need;
  unsigned short* T2   = (unsigned short*)alloc((size_t)FF * HID * 2);
  const bool fat = (ws_size >= need);
  if (ws_size < need_base) return;  // workspace too small: fail visibly

  // o-proj partials: gbuf and the dead xn+qkv region.
  float* pO0 = (float*)gbuf;
  float* pO1 = (float*)xn;
  // down-proj partials: fat -> T2 (wu dead by then); else ubuf + xn region.
  float* pD0 = fat ? (float*)T2 : (float*)ubuf;
  float* pD1 = fat ? (float*)(T2 + (size_t)SEQ * HID * 2) : (float*)xn;
  (void)ubuf;

  // 1) rmsnorm1
  rmsnorm_kernel<<<SEQ, 256, 0, stream>>>(hs, ln1, xn);
  // 2) transpose wq|wk|wv into T1 -> [QKVN][HID] bf16
  wtrans_kernel<<<dim3(HID / 64, HID / 64), 256, 0, stream>>>(wq, T1, HID, HID);
  wtrans_kernel<<<dim3(HID / 64, (NKV * DH) / 64), 256, 0, stream>>>(
      wk, T1 + (size_t)(NH * DH) * HID, HID, NKV * DH);
  wtrans_kernel<<<dim3(HID / 64, (NKV * DH) / 64), 256, 0, stream>>>(
      wvp, T1 + (size_t)(NH * DH + NKV * DH) * HID, HID, NKV * DH);
  // 3) fused qkv projection; fat: + wo-transpose tail (64 blocks) -> T2
  if (fat) {
    gemm8p_kernel<0><<<192 + 64, 512, 0, stream>>>(
        xn, T1, qkv, nullptr, SEQ / 256, QKVN, HID, 1, wo, T2, HID, HID, 64);
  } else {
    gemm8p_kernel<0><<<192, 512, 0, stream>>>(
        xn, T1, qkv, nullptr, SEQ / 256, QKVN, HID, 1, nullptr, nullptr, 64, 64, 0);
  }
  // 4) RoPE: Q+K head slots are contiguous (40 x 128 cols); V untouched
  rope_kernel<<<(SEQ * (NH + NKV) * 64) / 256, 256, 0, stream>>>(qkv, NH + NKV,
                                                                 QKVN);
  // 5) attention; fat: + wg-transpose tail (512 blocks) -> T1 (T1 dead after
  //    qkv GEMM; gate reads it two dispatches later). LPT raggedness absorbs
  //    the BW work.
  if (fat) {
    attn_kernel<<<512 + 512, 512, 0, stream>>>(qkv, ab, wg, T1, HID, FF, 512);
  } else {
    attn_kernel<<<512, 512, 0, stream>>>(qkv, ab, nullptr, nullptr, 64, 64, 0);
  }
  // 6) o-proj split-K=2 + fused combine+rmsnorm2 -> h2, xn2
  unsigned short* Wo = fat ? T2 : T1;
  if (!fat)
    wtrans_kernel<<<dim3(HID / 64, HID / 64), 256, 0, stream>>>(wo, T1, HID, HID);
  gemm8p_kernel<2><<<256, 512, 0, stream>>>(
      ab, Wo, pO0, pO1, SEQ / 256, HID, HID, 2, nullptr, nullptr, 64, 64, 0);
  combine_rms_kernel<<<SEQ, 256, 0, stream>>>(pO0, pO1, hs, ln2, h2, xn2);
  // 7) gate; fat: wg already transposed during attn; + wu-transpose tail -> T2
  if (fat) {
    gemm8p_kernel<0><<<448 + 1024, 512, 0, stream>>>(
        xn2, T1, gbuf, nullptr, SEQ / 256, FF, HID, 1, wu, T2, HID, FF, 1024);
  } else {
    wtrans_kernel<<<dim3(HID / 64, FF / 64), 256, 0, stream>>>(wg, T1, HID, FF);
    gemm8p_kernel<0><<<448, 512, 0, stream>>>(
        xn2, T1, gbuf, nullptr, SEQ / 256, FF, HID, 1, nullptr, nullptr, 64, 64, 0);
  }
  // 8) up with fused SiLU epilogue; fat: + wd-transpose tail -> T1 (wg dead)
  if (fat) {
    gemm8p_kernel<3><<<448 + 1024, 512, 0, stream>>>(
        xn2, T2, gbuf, gbuf, SEQ / 256, FF, HID, 1, wd, T1, FF, HID, 1024);
  } else {
    wtrans_kernel<<<dim3(HID / 64, FF / 64), 256, 0, stream>>>(wu, T1, HID, FF);
    gemm8p_kernel<3><<<448, 512, 0, stream>>>(
        xn2, T1, gbuf, gbuf, SEQ / 256, FF, HID, 1, nullptr, nullptr, 64, 64, 0);
  }
  // 9) down-proj split-K=2 + combine with residual h2 -> out
  if (!fat)
    wtrans_kernel<<<dim3(FF / 64, HID / 64), 256, 0, stream>>>(wd, T1, FF, HID);
  gemm8p_kernel<2><<<256, 512, 0, stream>>>(
      gbuf, T1, pD0, pD1, SEQ / 256, HID, FF, 2, nullptr, nullptr, 64, 64, 0);
  combine_kernel<<<(SEQ * HID) / 1024, 256, 0, stream>>>(pD0, pD1, h2,
                                                         (float*)d_out);
}